// Round 4
// baseline (262.090 us; speedup 1.0000x reference)
//
#include <hip/hip_runtime.h>

// Problem: N=32, C=512, H=W=32 (HW=1024), D=256.
// out = x + W_fuse * softmax((Wt x)^T (Wp x) / 16) applied to values x, per batch.
//
// Pipeline (all bf16 MFMA, fp32 accumulate):
//  k_packw : W_theta|W_phi -> Wcat bf16 [512][512], W_fuse -> bf16 [512][512]
//  k_prep  : x [n,c,q] fp32 -> xt [n,q,c] bf16 (transposed, pixel-major)
//  k_embed : tp[n,q,0:256]=theta, [256:512]=phi  (GEMM 32768x512x512)
//  k_cast  : x fp32 -> xb bf16 [n,c,q] (native layout), overwrites xt space
//  k_attn4 : flash-style per (n, 64-query tile), 8 waves, KV tiles of 128 keys.
//            P double-buffered in LDS -> ONE barrier per KV-iter; K fragments
//            prefetched into regs before the PV MFMA cluster; S(it+1) computed
//            in the same barrier-free region as PV(it). Grid = (n, qtile) so
//            XCD = n%8 (per-XCD K/V working set 6MB instead of 48MB).
//            Then rowsum-normalize -> Os LDS -> fused 1x1 conv + residual.
//
// Workspace (65 MB):
//   [0,32MB)    xt  (k_prep->k_embed), then xb (k_cast->k_attn4)
//   [32,64MB)   tp
//   [64MB,+512K)  Wcat bf16 ; [+512K,+1MB) Wfuse bf16

#define NB  32
#define CC  512
#define HWD 1024

typedef __attribute__((ext_vector_type(8))) short short8;
typedef __attribute__((ext_vector_type(4))) float f32x4;

__device__ __forceinline__ unsigned short f2bu(float f) {
    unsigned int u = __float_as_uint(f);
    u = (u + 0x7FFFu + ((u >> 16) & 1u)) >> 16;   // RNE to bf16
    return (unsigned short)u;
}

// ---------------- weights pack ----------------
__global__ __launch_bounds__(256) void k_packw(const float* __restrict__ Wt,
                                               const float* __restrict__ Wp,
                                               const float* __restrict__ Wf,
                                               unsigned short* __restrict__ Wcat,
                                               unsigned short* __restrict__ Wfuse) {
    int idx = blockIdx.x * 256 + threadIdx.x;       // 0 .. 262143
    int o = idx >> 9;
    float cv = (o < 256) ? Wt[idx] : Wp[idx - 131072];
    Wcat[idx]  = f2bu(cv);
    Wfuse[idx] = f2bu(Wf[idx]);
}

// ---------------- x transpose -> xt[n,q,c] bf16 ----------------
__global__ __launch_bounds__(256) void k_prep(const float* __restrict__ x,
                                              unsigned short* __restrict__ xt) {
    __shared__ float tile[32][33];
    const int n = blockIdx.z, c0 = blockIdx.y << 5, q0 = blockIdx.x << 5;
    const int t = threadIdx.x;
    const int r = t >> 3, j4 = (t & 7) << 2;
    const float* src = x + ((size_t)(n * CC + c0 + r)) * HWD + q0 + j4;
    float4 v = *(const float4*)src;
    tile[r][j4 + 0] = v.x; tile[r][j4 + 1] = v.y;
    tile[r][j4 + 2] = v.z; tile[r][j4 + 3] = v.w;
    __syncthreads();
    ushort4 uv;
    uv.x = f2bu(tile[j4 + 0][r]);
    uv.y = f2bu(tile[j4 + 1][r]);
    uv.z = f2bu(tile[j4 + 2][r]);
    uv.w = f2bu(tile[j4 + 3][r]);
    *(ushort4*)(xt + ((size_t)(n * HWD + q0 + r)) * CC + c0 + j4) = uv;
}

// ---------------- x -> xb bf16 (same layout) ----------------
__global__ __launch_bounds__(256) void k_cast(const float* __restrict__ x,
                                              unsigned short* __restrict__ xb) {
    const size_t i = ((size_t)blockIdx.x * 256 + threadIdx.x) * 8;
    float4 v0 = *(const float4*)(x + i);
    float4 v1 = *(const float4*)(x + i + 4);
    short8 o;
    o[0] = (short)f2bu(v0.x); o[1] = (short)f2bu(v0.y);
    o[2] = (short)f2bu(v0.z); o[3] = (short)f2bu(v0.w);
    o[4] = (short)f2bu(v1.x); o[5] = (short)f2bu(v1.y);
    o[6] = (short)f2bu(v1.z); o[7] = (short)f2bu(v1.w);
    *(short8*)(xb + i) = o;
}

// ---------------- embed GEMM: tp = xt * Wcat^T + bias ----------------
__global__ __launch_bounds__(256) void k_embed(const unsigned short* __restrict__ xt,
                                               const unsigned short* __restrict__ Wcat,
                                               const float* __restrict__ bt,
                                               const float* __restrict__ bp,
                                               unsigned short* __restrict__ tp) {
    __shared__ __align__(16) unsigned short As[128 * 40];
    __shared__ __align__(16) unsigned short Bs[128 * 40];
    const int m0 = blockIdx.x << 7, n0 = blockIdx.y << 7;
    const int t = threadIdx.x, lane = t & 63, wave = t >> 6;
    const int wr = wave >> 1, wc = wave & 1;
    const int lrow = lane & 15, hi = lane >> 4, lhk = hi << 3;
    const f32x4 fz = {0.f, 0.f, 0.f, 0.f};
    f32x4 acc[4][4];
#pragma unroll
    for (int i = 0; i < 4; ++i)
#pragma unroll
        for (int j = 0; j < 4; ++j) acc[i][j] = fz;

    for (int kt = 0; kt < 16; ++kt) {
        const int k0 = kt << 5;
#pragma unroll
        for (int i = 0; i < 2; ++i) {
            int chunk = t + (i << 8);
            int r = chunk >> 2, ko = (chunk & 3) << 3;
            *(uint4*)(As + r * 40 + ko) =
                *(const uint4*)(xt + ((size_t)(m0 + r)) * CC + k0 + ko);
            *(uint4*)(Bs + r * 40 + ko) =
                *(const uint4*)(Wcat + ((size_t)(n0 + r)) * CC + k0 + ko);
        }
        __syncthreads();
        short8 af[4], bfm[4];
#pragma unroll
        for (int mi = 0; mi < 4; ++mi)
            af[mi] = *(const short8*)(As + (wr * 64 + mi * 16 + lrow) * 40 + lhk);
#pragma unroll
        for (int ni = 0; ni < 4; ++ni)
            bfm[ni] = *(const short8*)(Bs + (wc * 64 + ni * 16 + lrow) * 40 + lhk);
#pragma unroll
        for (int mi = 0; mi < 4; ++mi)
#pragma unroll
            for (int ni = 0; ni < 4; ++ni)
                acc[mi][ni] = __builtin_amdgcn_mfma_f32_16x16x32_bf16(
                    af[mi], bfm[ni], acc[mi][ni], 0, 0, 0);
        __syncthreads();
    }
#pragma unroll
    for (int ni = 0; ni < 4; ++ni) {
        const int col = n0 + wc * 64 + ni * 16 + lrow;
        const float bias = (col < 256) ? bt[col] : bp[col - 256];
#pragma unroll
        for (int mi = 0; mi < 4; ++mi)
#pragma unroll
            for (int j = 0; j < 4; ++j) {
                const int row = m0 + wr * 64 + mi * 16 + hi * 4 + j;
                tp[(size_t)row * CC + col] = f2bu(acc[mi][ni][j] + bias);
            }
    }
}

// ---------------- flash attention + fuse conv + residual ----------------
// 8 waves, 64-query tile, KV tiles of 128 keys, P double-buffered.
__global__ __launch_bounds__(512, 4) void k_attn4(const unsigned short* __restrict__ tp,
                                                  const unsigned short* __restrict__ xb,
                                                  const unsigned short* __restrict__ Wfuse,
                                                  const float* __restrict__ bfu,
                                                  const float* __restrict__ x,
                                                  float* __restrict__ out) {
    constexpr int QST = 264;                       // Q row stride (bf16)
    constexpr int PST = 136;                       // P row stride (bf16)
    constexpr int OST = 520;                       // Os row stride (bf16)
    constexpr int QSZ = 64 * QST;                  // 16896 elems
    constexpr int PSZ = 64 * PST;                  // 8704 elems
    __shared__ __align__(16) unsigned short SL[QSZ + 2 * PSZ];   // 68,608 B
    __shared__ float rowsum[64];
    unsigned short* Qs = SL;                       // [64][264]
    unsigned short* Os = SL;                       // overlay [64][520] (33280 el)

    const int n = blockIdx.x, q0 = blockIdx.y << 6;   // XCD = n % 8
    const int t = threadIdx.x, lane = t & 63, wave = t >> 6;
    const int lrow = lane & 15, hi = lane >> 4, lhk = hi << 3;
    const f32x4 fz = {0.f, 0.f, 0.f, 0.f};

    const unsigned short* tpn = tp + (size_t)n * HWD * CC;
    const unsigned short* xbn = xb + (size_t)n * CC * HWD;

    if (t < 64) rowsum[t] = 0.f;
    // stage Q tile: rows q0..q0+63, d 0..255
#pragma unroll
    for (int pass = 0; pass < 4; ++pass) {
        int chunk = (pass << 9) + t;               // 0..2047
        int row = chunk >> 5, co = (chunk & 31) << 3;
        *(short8*)(Qs + row * QST + co) =
            *(const short8*)(tpn + (size_t)(q0 + row) * CC + co);
    }
    __syncthreads();

    f32x4 accO[4][4];
#pragma unroll
    for (int qj = 0; qj < 4; ++qj)
#pragma unroll
        for (int ci = 0; ci < 4; ++ci) accO[qj][ci] = fz;
    float psum[4][4];
#pragma unroll
    for (int qj = 0; qj < 4; ++qj)
#pragma unroll
        for (int j = 0; j < 4; ++j) psum[qj][j] = 0.f;

    const int kw = wave << 4;                      // wave's 16-key slot in tile
    const int cw = wave << 6;                      // wave's 64-channel range

    // ---- prologue: S(0) with direct K loads -> P[0] ----
    {
        f32x4 accA[4];
#pragma unroll
        for (int qj = 0; qj < 4; ++qj) accA[qj] = fz;
#pragma unroll
        for (int kt = 0; kt < 8; ++kt) {
            const int d0 = (kt << 5) + lhk;
            short8 kfr = *(const short8*)(tpn + (size_t)(kw + lrow) * CC + 256 + d0);
#pragma unroll
            for (int qj = 0; qj < 4; ++qj) {
                short8 qfr = *(const short8*)(Qs + (qj * 16 + lrow) * QST + d0);
                accA[qj] = __builtin_amdgcn_mfma_f32_16x16x32_bf16(qfr, kfr, accA[qj], 0, 0, 0);
            }
        }
        unsigned short* P0 = SL + QSZ;
#pragma unroll
        for (int qj = 0; qj < 4; ++qj)
#pragma unroll
            for (int j = 0; j < 4; ++j) {
                float p = __expf(accA[qj][j] * 0.0625f);
                psum[qj][j] += p;
                P0[(qj * 16 + hi * 4 + j) * PST + kw + lrow] = f2bu(p);
            }
    }

    for (int it = 0; it < 8; ++it) {
        __syncthreads();                           // P[it&1] visible to all
        const int kv0 = it << 7;
        // prefetch first half of K(it+1) into regs (hidden under PV MFMAs)
        short8 kpre[4];
        if (it < 7) {
            const size_t kn = (size_t)(((it + 1) << 7) + kw + lrow) * CC + 256;
#pragma unroll
            for (int kt = 0; kt < 4; ++kt)
                kpre[kt] = *(const short8*)(tpn + kn + (kt << 5) + lhk);
        }
        const unsigned short* Pc = SL + QSZ + (it & 1) * PSZ;
        // ---- PV(it): O += P V^T ----
        __builtin_amdgcn_s_setprio(1);
#pragma unroll
        for (int ks = 0; ks < 4; ++ks) {
            const int kb = (ks << 5) + lhk;
            short8 pa[4];
#pragma unroll
            for (int qj = 0; qj < 4; ++qj)
                pa[qj] = *(const short8*)(Pc + (qj * 16 + lrow) * PST + kb);
#pragma unroll
            for (int ci = 0; ci < 4; ++ci) {
                short8 vf = *(const short8*)(xbn + (size_t)(cw + ci * 16 + lrow) * HWD + kv0 + kb);
#pragma unroll
                for (int qj = 0; qj < 4; ++qj)
                    accO[qj][ci] = __builtin_amdgcn_mfma_f32_16x16x32_bf16(pa[qj], vf, accO[qj][ci], 0, 0, 0);
            }
        }
        __builtin_amdgcn_s_setprio(0);
        // ---- S(it+1) -> P[(it+1)&1] (no barrier needed: other buffer) ----
        if (it < 7) {
            unsigned short* Pn = SL + QSZ + ((it + 1) & 1) * PSZ;
            const size_t kn = (size_t)(((it + 1) << 7) + kw + lrow) * CC + 256;
            f32x4 accA[4];
#pragma unroll
            for (int qj = 0; qj < 4; ++qj) accA[qj] = fz;
            __builtin_amdgcn_s_setprio(1);
#pragma unroll
            for (int kt = 0; kt < 4; ++kt) {
                const int d0 = (kt << 5) + lhk;
#pragma unroll
                for (int qj = 0; qj < 4; ++qj) {
                    short8 qfr = *(const short8*)(Qs + (qj * 16 + lrow) * QST + d0);
                    accA[qj] = __builtin_amdgcn_mfma_f32_16x16x32_bf16(qfr, kpre[kt], accA[qj], 0, 0, 0);
                }
            }
#pragma unroll
            for (int kt = 4; kt < 8; ++kt) {
                const int d0 = (kt << 5) + lhk;
                short8 kfr = *(const short8*)(tpn + kn + (kt << 5) + lhk);
#pragma unroll
                for (int qj = 0; qj < 4; ++qj) {
                    short8 qfr = *(const short8*)(Qs + (qj * 16 + lrow) * QST + d0);
                    accA[qj] = __builtin_amdgcn_mfma_f32_16x16x32_bf16(qfr, kfr, accA[qj], 0, 0, 0);
                }
            }
            __builtin_amdgcn_s_setprio(0);
#pragma unroll
            for (int qj = 0; qj < 4; ++qj)
#pragma unroll
                for (int j = 0; j < 4; ++j) {
                    float p = __expf(accA[qj][j] * 0.0625f);
                    psum[qj][j] += p;
                    Pn[(qj * 16 + hi * 4 + j) * PST + kw + lrow] = f2bu(p);
                }
        }
    }

    // ---- row sums across waves ----
#pragma unroll
    for (int qj = 0; qj < 4; ++qj)
#pragma unroll
        for (int j = 0; j < 4; ++j) {
            float s = psum[qj][j];
            s += __shfl_xor(s, 1, 16);
            s += __shfl_xor(s, 2, 16);
            s += __shfl_xor(s, 4, 16);
            s += __shfl_xor(s, 8, 16);
            if (lrow == 0) atomicAdd(&rowsum[qj * 16 + hi * 4 + j], s);
        }
    __syncthreads();                               // rowsum complete; P/Q reads done

    // ---- normalize -> Os (overlays Q/P) ----
    float inv[4][4];
#pragma unroll
    for (int qj = 0; qj < 4; ++qj)
#pragma unroll
        for (int j = 0; j < 4; ++j)
            inv[qj][j] = 1.f / rowsum[qj * 16 + hi * 4 + j];
#pragma unroll
    for (int qj = 0; qj < 4; ++qj)
#pragma unroll
        for (int ci = 0; ci < 4; ++ci) {
            const int c = cw + (ci << 4) + lrow;
#pragma unroll
            for (int j = 0; j < 4; ++j)
                Os[(qj * 16 + hi * 4 + j) * OST + c] = f2bu(accO[qj][ci][j] * inv[qj][j]);
        }
    __syncthreads();

    // ---- fuse conv: out[n, o, q] = x + b_fuse[o] + W_fuse . O ----
    f32x4 accF[4][4];
#pragma unroll
    for (int mi = 0; mi < 4; ++mi)
#pragma unroll
        for (int qj = 0; qj < 4; ++qj) accF[mi][qj] = fz;
    const int ob = wave << 6;                      // wave's 64-output range
    for (int kt = 0; kt < 16; ++kt) {
        const int k0 = (kt << 5) + lhk;
        short8 bq[4];
#pragma unroll
        for (int qj = 0; qj < 4; ++qj)
            bq[qj] = *(const short8*)(Os + (qj * 16 + lrow) * OST + k0);
        __builtin_amdgcn_s_setprio(1);
#pragma unroll
        for (int mi = 0; mi < 4; ++mi) {
            short8 af = *(const short8*)(Wfuse + (size_t)(ob + (mi << 4) + lrow) * CC + k0);
#pragma unroll
            for (int qj = 0; qj < 4; ++qj)
                accF[mi][qj] = __builtin_amdgcn_mfma_f32_16x16x32_bf16(af, bq[qj], accF[mi][qj], 0, 0, 0);
        }
        __builtin_amdgcn_s_setprio(0);
    }
#pragma unroll
    for (int mi = 0; mi < 4; ++mi) {
#pragma unroll
        for (int j = 0; j < 4; ++j) {
            const int o = ob + (mi << 4) + hi * 4 + j;
            const float bias = bfu[o];
#pragma unroll
            for (int qj = 0; qj < 4; ++qj) {
                const int q = q0 + qj * 16 + lrow;
                const size_t idx = ((size_t)(n * CC + o)) * HWD + q;
                out[idx] = accF[mi][qj][j] + bias + x[idx];
            }
        }
    }
}

extern "C" void kernel_launch(void* const* d_in, const int* in_sizes, int n_in,
                              void* d_out, int out_size, void* d_ws, size_t ws_size,
                              hipStream_t stream) {
    const float* x  = (const float*)d_in[0];
    const float* Wt = (const float*)d_in[1];
    const float* bt = (const float*)d_in[2];
    const float* Wp = (const float*)d_in[3];
    const float* bp = (const float*)d_in[4];
    const float* Wf = (const float*)d_in[5];
    const float* bfu = (const float*)d_in[6];
    float* out = (float*)d_out;

    char* ws = (char*)d_ws;
    unsigned short* xt_xb = (unsigned short*)(ws);                 // 32 MB (xt, later xb)
    unsigned short* tp    = (unsigned short*)(ws + 33554432);      // 32 MB
    unsigned short* Wcat  = (unsigned short*)(ws + 67108864);      // 512 KB
    unsigned short* Wfuse = (unsigned short*)(ws + 67633152);      // 512 KB

    k_packw<<<dim3(1024), 256, 0, stream>>>(Wt, Wp, Wf, Wcat, Wfuse);
    k_prep <<<dim3(32, 16, 32), 256, 0, stream>>>(x, xt_xb);
    k_embed<<<dim3(256, 4), 256, 0, stream>>>(xt_xb, Wcat, bt, bp, tp);
    k_cast <<<dim3(8192), 256, 0, stream>>>(x, xt_xb);             // xb overwrites xt
    k_attn4<<<dim3(32, 16), 512, 0, stream>>>(tp, xt_xb, Wfuse, bfu, x, out);
}